// Round 2
// baseline (7232.653 us; speedup 1.0000x reference)
//
#include <hip/hip_runtime.h>
#include <math.h>

// ---------------------------------------------------------------------------
// APPNP + 3-layer GCN on MI355X.
// Pipeline per launch (must redo ALL work each call):
//   1. CSR build by dst (counting sort): deg count -> exclusive scan ->
//      fill (self-loops + edges) with per-row slot counters. norm = dinv*dinv.
//   2. 3x { fp32 tiled GEMM (N x 256 @ 256 x 256) ; SpMM with fused bias+ReLU }
//   3. 10x APPNP SpMM with fused 0.9*sum + 0.1*h0
//   4. final 256->40 linear + log_softmax fused (fc_w in LDS)
// Workspace layout: cnt(N) rowptr(N+1) dinv(N) edges(8B*(E+N)) bufA/B/C(N*256 f32)
// ~335 MB total.
// ---------------------------------------------------------------------------

constexpr int D = 256;   // feature / hidden dim
constexpr int C = 40;    // classes

struct __align__(8) EdgeCV { int c; float v; };

// ---- CSR build ------------------------------------------------------------

__global__ void k_init_cnt(int* __restrict__ cnt, int N) {
    int i = blockIdx.x * blockDim.x + threadIdx.x;
    if (i < N) cnt[i] = 1;            // self loop contributes 1 to in-degree
}

__global__ void k_count(const int* __restrict__ dst, int* __restrict__ cnt, int E) {
    int e = blockIdx.x * blockDim.x + threadIdx.x;
    if (e < E) atomicAdd(&cnt[dst[e]], 1);
}

// single-block exclusive scan over N counts -> rowptr[0..N]
__global__ __launch_bounds__(1024) void k_scan(const int* __restrict__ cnt,
                                               int* __restrict__ rowptr, int N) {
    __shared__ int sm[1024];
    const int tid = threadIdx.x;
    int offset = 0;
    for (int base = 0; base < N; base += 1024) {
        int i = base + tid;
        int v = (i < N) ? cnt[i] : 0;
        sm[tid] = v;
        #pragma unroll 1
        for (int s = 1; s < 1024; s <<= 1) {
            __syncthreads();
            int t = (tid >= s) ? sm[tid - s] : 0;
            __syncthreads();
            sm[tid] += t;
        }
        int incl = sm[tid];           // own value, no sync needed
        if (i < N) rowptr[i] = offset + incl - v;
        __syncthreads();
        offset += sm[1023];
        __syncthreads();              // protect sm reuse next iteration
    }
    if (tid == 0) rowptr[N] = offset;
}

__global__ void k_dinv(const int* __restrict__ cnt, float* __restrict__ dinv, int N) {
    int i = blockIdx.x * blockDim.x + threadIdx.x;
    if (i < N) dinv[i] = rsqrtf((float)cnt[i]);   // deg >= 1 always (self loop)
}

__global__ void k_fill_self(const int* __restrict__ rowptr, const float* __restrict__ dinv,
                            EdgeCV* __restrict__ edges, int* __restrict__ fill, int N) {
    int i = blockIdx.x * blockDim.x + threadIdx.x;
    if (i < N) {
        float dv = dinv[i];
        EdgeCV e; e.c = i; e.v = dv * dv;
        edges[rowptr[i]] = e;
        fill[i] = 1;                  // slot 0 consumed by self loop
    }
}

__global__ void k_fill_edges(const int* __restrict__ src, const int* __restrict__ dst,
                             const int* __restrict__ rowptr, const float* __restrict__ dinv,
                             EdgeCV* __restrict__ edges, int* __restrict__ fill, int E) {
    int e = blockIdx.x * blockDim.x + threadIdx.x;
    if (e < E) {
        int s = src[e], d = dst[e];
        int slot = atomicAdd(&fill[d], 1);
        EdgeCV ev; ev.c = s; ev.v = dinv[s] * dinv[d];
        edges[rowptr[d] + slot] = ev;
    }
}

// ---- fp32 tiled GEMM: Cout[M x 256] = A[M x 256] @ W[256 x 256] -----------

#define BM 128
#define BN 64
#define BK 16

__global__ __launch_bounds__(256) void k_gemm(const float* __restrict__ A,
                                              const float* __restrict__ W,
                                              float* __restrict__ Cout, int M) {
    __shared__ float As[BK][BM + 4];   // +4 pad keeps 16B alignment (132*4=528=33*16)
    __shared__ float Bs[BK][BN + 4];   // 68*4=272=17*16
    const int tid = threadIdx.x;
    const int tx = tid & 15;           // 0..15 -> 4 cols each
    const int ty = tid >> 4;           // 0..15 -> 8 rows each
    const int m0 = blockIdx.x * BM;
    const int n0 = blockIdx.y * BN;
    float acc[8][4] = {};
    for (int kb = 0; kb < D; kb += BK) {
        #pragma unroll
        for (int r = 0; r < 2; ++r) {  // A tile: 128x16 = 512 float4
            int idx = tid + r * 256;
            int row = idx >> 2;
            int kq  = idx & 3;
            int grow = m0 + row;
            float4 a = make_float4(0.f, 0.f, 0.f, 0.f);
            if (grow < M) a = *(const float4*)(&A[(size_t)grow * D + kb + kq * 4]);
            As[kq * 4 + 0][row] = a.x;
            As[kq * 4 + 1][row] = a.y;
            As[kq * 4 + 2][row] = a.z;
            As[kq * 4 + 3][row] = a.w;
        }
        {                              // W tile: 16x64 = 256 float4
            int k  = tid >> 4;
            int nq = tid & 15;
            float4 b = *(const float4*)(&W[(size_t)(kb + k) * D + n0 + nq * 4]);
            *(float4*)(&Bs[k][nq * 4]) = b;
        }
        __syncthreads();
        #pragma unroll
        for (int k = 0; k < BK; ++k) {
            float a[8], b[4];
            *(float4*)&a[0] = *(const float4*)(&As[k][ty * 8]);
            *(float4*)&a[4] = *(const float4*)(&As[k][ty * 8 + 4]);
            *(float4*)&b[0] = *(const float4*)(&Bs[k][tx * 4]);
            #pragma unroll
            for (int i = 0; i < 8; ++i)
                #pragma unroll
                for (int j = 0; j < 4; ++j)
                    acc[i][j] += a[i] * b[j];
        }
        __syncthreads();
    }
    #pragma unroll
    for (int i = 0; i < 8; ++i) {
        int grow = m0 + ty * 8 + i;
        if (grow < M)
            *(float4*)(&Cout[(size_t)grow * D + n0 + tx * 4]) = *(float4*)&acc[i][0];
    }
}

// ---- SpMM: out[i,:] = sum_e val[e] * h[col[e],:], wave per row ------------
// MODE 0: out = relu(sum + bias)         (aux = bias[256])
// MODE 1: out = 0.9*sum + 0.1*h0[i,:]    (aux = h0)

template <int MODE>
__global__ __launch_bounds__(256) void k_spmm(const float* __restrict__ h,
                                              const int* __restrict__ rowptr,
                                              const EdgeCV* __restrict__ edges,
                                              const float* __restrict__ aux,
                                              float* __restrict__ out, int N) {
    int gid  = (int)((blockIdx.x * (unsigned)blockDim.x + threadIdx.x) >> 6);
    int lane = threadIdx.x & 63;
    if (gid >= N) return;
    int start = rowptr[gid], end = rowptr[gid + 1];
    float4 acc = make_float4(0.f, 0.f, 0.f, 0.f);
    const float4* hp = (const float4*)h;
    for (int e = start; e < end; ++e) {
        EdgeCV cv = edges[e];                       // wave-uniform 8B load
        float4 x = hp[(size_t)cv.c * 64 + lane];    // coalesced 1KB/wave gather
        acc.x += cv.v * x.x;
        acc.y += cv.v * x.y;
        acc.z += cv.v * x.z;
        acc.w += cv.v * x.w;
    }
    if (MODE == 0) {
        float4 b = ((const float4*)aux)[lane];
        acc.x = fmaxf(acc.x + b.x, 0.f);
        acc.y = fmaxf(acc.y + b.y, 0.f);
        acc.z = fmaxf(acc.z + b.z, 0.f);
        acc.w = fmaxf(acc.w + b.w, 0.f);
    } else {
        float4 h0 = ((const float4*)aux)[(size_t)gid * 64 + lane];
        acc.x = 0.9f * acc.x + 0.1f * h0.x;
        acc.y = 0.9f * acc.y + 0.1f * h0.y;
        acc.z = 0.9f * acc.z + 0.1f * h0.z;
        acc.w = 0.9f * acc.w + 0.1f * h0.w;
    }
    ((float4*)out)[(size_t)gid * 64 + lane] = acc;
}

// ---- final: logits = h @ fc_w + fc_b ; log_softmax ------------------------

__global__ __launch_bounds__(256) void k_final(const float* __restrict__ h,
                                               const float* __restrict__ fcw,
                                               const float* __restrict__ fcb,
                                               float* __restrict__ out, int N) {
    __shared__ float ws[D * C];        // 40 KB
    __shared__ float bs[C];
    for (int i = threadIdx.x; i < D * C; i += blockDim.x) ws[i] = fcw[i];
    for (int i = threadIdx.x; i < C; i += blockDim.x) bs[i] = fcb[i];
    __syncthreads();
    int row = blockIdx.x * blockDim.x + threadIdx.x;
    if (row >= N) return;
    float acc[C];
    #pragma unroll
    for (int c = 0; c < C; ++c) acc[c] = bs[c];
    const float* hr = h + (size_t)row * D;
    for (int k = 0; k < D; ++k) {
        float hv = hr[k];
        #pragma unroll
        for (int c = 0; c < C; ++c) acc[c] += hv * ws[k * C + c];   // LDS broadcast
    }
    float m = acc[0];
    #pragma unroll
    for (int c = 1; c < C; ++c) m = fmaxf(m, acc[c]);
    float s = 0.f;
    #pragma unroll
    for (int c = 0; c < C; ++c) s += expf(acc[c] - m);
    float lse = logf(s) + m;
    float* orow = out + (size_t)row * C;
    #pragma unroll
    for (int c = 0; c < C; ++c) orow[c] = acc[c] - lse;
}

// ---------------------------------------------------------------------------

extern "C" void kernel_launch(void* const* d_in, const int* in_sizes, int n_in,
                              void* d_out, int out_size, void* d_ws, size_t ws_size,
                              hipStream_t stream) {
    const float* x   = (const float*)d_in[0];
    const int*   ei  = (const int*)d_in[1];
    const float* w1  = (const float*)d_in[2];
    const float* b1  = (const float*)d_in[3];
    const float* w2  = (const float*)d_in[4];
    const float* b2  = (const float*)d_in[5];
    const float* w3  = (const float*)d_in[6];
    const float* b3  = (const float*)d_in[7];
    const float* fcw = (const float*)d_in[8];
    const float* fcb = (const float*)d_in[9];
    float* out = (float*)d_out;

    const int N = in_sizes[0] / D;
    const int E = in_sizes[1] / 2;
    const int* srcArr = ei;
    const int* dstArr = ei + E;

    char* wsp = (char*)d_ws;
    size_t off = 0;
    auto take = [&](size_t bytes) -> void* {
        void* p = wsp + off;
        off = (off + bytes + 255) & ~(size_t)255;
        return p;
    };
    int*    cnt    = (int*)take((size_t)N * 4);
    int*    rowptr = (int*)take((size_t)(N + 1) * 4);
    float*  dinv   = (float*)take((size_t)N * 4);
    EdgeCV* edges  = (EdgeCV*)take((size_t)(E + N) * 8);
    float*  bufA   = (float*)take((size_t)N * D * 4);
    float*  bufB   = (float*)take((size_t)N * D * 4);
    float*  bufC   = (float*)take((size_t)N * D * 4);
    (void)ws_size;

    dim3 b256(256);
    int gN = (N + 255) / 256;
    int gE = (E + 255) / 256;

    // CSR build
    k_init_cnt<<<gN, b256, 0, stream>>>(cnt, N);
    k_count<<<gE, b256, 0, stream>>>(dstArr, cnt, E);
    k_scan<<<1, 1024, 0, stream>>>(cnt, rowptr, N);
    k_dinv<<<gN, b256, 0, stream>>>(cnt, dinv, N);
    k_fill_self<<<gN, b256, 0, stream>>>(rowptr, dinv, edges, cnt, N);
    k_fill_edges<<<gE, b256, 0, stream>>>(srcArr, dstArr, rowptr, dinv, edges, cnt, E);

    dim3 gemmGrid((N + BM - 1) / BM, D / BN);
    int spBlocks = (N + 3) / 4;        // 4 waves/block, wave per row

    // GCN layer 1..3 (bias+relu fused into SpMM epilogue)
    k_gemm<<<gemmGrid, b256, 0, stream>>>(x, w1, bufA, N);
    k_spmm<0><<<spBlocks, b256, 0, stream>>>(bufA, rowptr, edges, b1, bufB, N);
    k_gemm<<<gemmGrid, b256, 0, stream>>>(bufB, w2, bufA, N);
    k_spmm<0><<<spBlocks, b256, 0, stream>>>(bufA, rowptr, edges, b2, bufB, N);
    k_gemm<<<gemmGrid, b256, 0, stream>>>(bufB, w3, bufA, N);
    k_spmm<0><<<spBlocks, b256, 0, stream>>>(bufA, rowptr, edges, b3, bufC, N);  // h0

    // APPNP: h <- 0.9 * A_hat h + 0.1 * h0
    const float* cur = bufC;
    float* nxt = bufA;
    for (int it = 0; it < 10; ++it) {
        k_spmm<1><<<spBlocks, b256, 0, stream>>>(cur, rowptr, edges, bufC, nxt, N);
        cur = nxt;
        nxt = (nxt == bufA) ? bufB : bufA;
    }

    // final linear + log_softmax
    k_final<<<gN, b256, 0, stream>>>(cur, fcw, fcb, out, N);
}

// Round 3
// 4283.794 us; speedup vs baseline: 1.6884x; 1.6884x over previous
//
#include <hip/hip_runtime.h>
#include <math.h>

// ---------------------------------------------------------------------------
// APPNP + 3-layer GCN on MI355X.
// Round 2 change: all intermediate h buffers in fp16 (_Float16) so the APPNP
// working set (cur + h0 + out = 150 MB) fits the 256 MB Infinity Cache.
// SpMM gather volume halves and becomes L3-served instead of HBM-served.
// GEMMs accumulate fp32 (load-convert), round once to fp16 on store.
// ---------------------------------------------------------------------------

constexpr int D = 256;   // feature / hidden dim
constexpr int C = 40;    // classes

typedef _Float16 h4 __attribute__((ext_vector_type(4)));

struct __align__(8) EdgeCV { int c; float v; };

__device__ inline float4 h4_to_f4(h4 x) {
    return make_float4((float)x[0], (float)x[1], (float)x[2], (float)x[3]);
}
__device__ inline h4 f4_to_h4(float4 x) {
    h4 r; r[0] = (_Float16)x.x; r[1] = (_Float16)x.y; r[2] = (_Float16)x.z; r[3] = (_Float16)x.w;
    return r;
}

// ---- CSR build ------------------------------------------------------------

__global__ void k_init_cnt(int* __restrict__ cnt, int N) {
    int i = blockIdx.x * blockDim.x + threadIdx.x;
    if (i < N) cnt[i] = 1;            // self loop contributes 1 to in-degree
}

__global__ void k_count(const int* __restrict__ dst, int* __restrict__ cnt, int E) {
    int e = blockIdx.x * blockDim.x + threadIdx.x;
    if (e < E) atomicAdd(&cnt[dst[e]], 1);
}

// single-block exclusive scan over N counts -> rowptr[0..N]
__global__ __launch_bounds__(1024) void k_scan(const int* __restrict__ cnt,
                                               int* __restrict__ rowptr, int N) {
    __shared__ int sm[1024];
    const int tid = threadIdx.x;
    int offset = 0;
    for (int base = 0; base < N; base += 1024) {
        int i = base + tid;
        int v = (i < N) ? cnt[i] : 0;
        sm[tid] = v;
        #pragma unroll 1
        for (int s = 1; s < 1024; s <<= 1) {
            __syncthreads();
            int t = (tid >= s) ? sm[tid - s] : 0;
            __syncthreads();
            sm[tid] += t;
        }
        int incl = sm[tid];
        if (i < N) rowptr[i] = offset + incl - v;
        __syncthreads();
        offset += sm[1023];
        __syncthreads();
    }
    if (tid == 0) rowptr[N] = offset;
}

__global__ void k_dinv(const int* __restrict__ cnt, float* __restrict__ dinv, int N) {
    int i = blockIdx.x * blockDim.x + threadIdx.x;
    if (i < N) dinv[i] = rsqrtf((float)cnt[i]);
}

__global__ void k_fill_self(const int* __restrict__ rowptr, const float* __restrict__ dinv,
                            EdgeCV* __restrict__ edges, int* __restrict__ fill, int N) {
    int i = blockIdx.x * blockDim.x + threadIdx.x;
    if (i < N) {
        float dv = dinv[i];
        EdgeCV e; e.c = i; e.v = dv * dv;
        edges[rowptr[i]] = e;
        fill[i] = 1;
    }
}

__global__ void k_fill_edges(const int* __restrict__ src, const int* __restrict__ dst,
                             const int* __restrict__ rowptr, const float* __restrict__ dinv,
                             EdgeCV* __restrict__ edges, int* __restrict__ fill, int E) {
    int e = blockIdx.x * blockDim.x + threadIdx.x;
    if (e < E) {
        int s = src[e], d = dst[e];
        int slot = atomicAdd(&fill[d], 1);
        EdgeCV ev; ev.c = s; ev.v = dinv[s] * dinv[d];
        edges[rowptr[d] + slot] = ev;
    }
}

// ---- tiled GEMM: Cout_fp16[M x 256] = A[M x 256] @ W[256 x 256] -----------
// TIN = float (layer 1) or _Float16 (layers 2,3). fp32 accumulate.

#define BM 128
#define BN 64
#define BK 16

template <typename TIN>
__global__ __launch_bounds__(256) void k_gemm(const TIN* __restrict__ A,
                                              const float* __restrict__ W,
                                              _Float16* __restrict__ Cout, int M) {
    __shared__ float As[BK][BM + 4];
    __shared__ float Bs[BK][BN + 4];
    const int tid = threadIdx.x;
    const int tx = tid & 15;
    const int ty = tid >> 4;
    const int m0 = blockIdx.x * BM;
    const int n0 = blockIdx.y * BN;
    float acc[8][4] = {};
    for (int kb = 0; kb < D; kb += BK) {
        #pragma unroll
        for (int r = 0; r < 2; ++r) {  // A tile: 128x16
            int idx = tid + r * 256;
            int row = idx >> 2;
            int kq  = idx & 3;
            int grow = m0 + row;
            float4 a = make_float4(0.f, 0.f, 0.f, 0.f);
            if (grow < M) {
                if constexpr (sizeof(TIN) == 2) {
                    h4 t = *(const h4*)(&A[(size_t)grow * D + kb + kq * 4]);
                    a = h4_to_f4(t);
                } else {
                    a = *(const float4*)(&A[(size_t)grow * D + kb + kq * 4]);
                }
            }
            As[kq * 4 + 0][row] = a.x;
            As[kq * 4 + 1][row] = a.y;
            As[kq * 4 + 2][row] = a.z;
            As[kq * 4 + 3][row] = a.w;
        }
        {                              // W tile: 16x64
            int k  = tid >> 4;
            int nq = tid & 15;
            float4 b = *(const float4*)(&W[(size_t)(kb + k) * D + n0 + nq * 4]);
            *(float4*)(&Bs[k][nq * 4]) = b;
        }
        __syncthreads();
        #pragma unroll
        for (int k = 0; k < BK; ++k) {
            float a[8], b[4];
            *(float4*)&a[0] = *(const float4*)(&As[k][ty * 8]);
            *(float4*)&a[4] = *(const float4*)(&As[k][ty * 8 + 4]);
            *(float4*)&b[0] = *(const float4*)(&Bs[k][tx * 4]);
            #pragma unroll
            for (int i = 0; i < 8; ++i)
                #pragma unroll
                for (int j = 0; j < 4; ++j)
                    acc[i][j] += a[i] * b[j];
        }
        __syncthreads();
    }
    #pragma unroll
    for (int i = 0; i < 8; ++i) {
        int grow = m0 + ty * 8 + i;
        if (grow < M) {
            float4 v = *(float4*)&acc[i][0];
            *(h4*)(&Cout[(size_t)grow * D + n0 + tx * 4]) = f4_to_h4(v);
        }
    }
}

// ---- SpMM: out[i,:] = sum_e val[e] * h[col[e],:], wave per row, fp16 h ----
// MODE 0: out = relu(sum + bias)         (auxf = bias[256] fp32)
// MODE 1: out = 0.9*sum + 0.1*h0[i,:]    (auxh = h0 fp16)

template <int MODE>
__global__ __launch_bounds__(256) void k_spmm(const _Float16* __restrict__ h,
                                              const int* __restrict__ rowptr,
                                              const EdgeCV* __restrict__ edges,
                                              const float* __restrict__ auxf,
                                              const _Float16* __restrict__ auxh,
                                              _Float16* __restrict__ out, int N) {
    int gid  = (int)((blockIdx.x * (unsigned)blockDim.x + threadIdx.x) >> 6);
    int lane = threadIdx.x & 63;
    if (gid >= N) return;
    int start = rowptr[gid], end = rowptr[gid + 1];
    const h4* hp = (const h4*)h;
    float4 acc0 = make_float4(0.f, 0.f, 0.f, 0.f);
    float4 acc1 = make_float4(0.f, 0.f, 0.f, 0.f);
    int e = start;
    // 2-wide unroll: two independent gathers in flight per iteration
    for (; e + 1 < end; e += 2) {
        EdgeCV c0 = edges[e];
        EdgeCV c1 = edges[e + 1];
        h4 x0 = hp[(size_t)c0.c * 64 + lane];
        h4 x1 = hp[(size_t)c1.c * 64 + lane];
        float4 f0 = h4_to_f4(x0), f1 = h4_to_f4(x1);
        acc0.x += c0.v * f0.x; acc0.y += c0.v * f0.y;
        acc0.z += c0.v * f0.z; acc0.w += c0.v * f0.w;
        acc1.x += c1.v * f1.x; acc1.y += c1.v * f1.y;
        acc1.z += c1.v * f1.z; acc1.w += c1.v * f1.w;
    }
    if (e < end) {
        EdgeCV c0 = edges[e];
        h4 x0 = hp[(size_t)c0.c * 64 + lane];
        float4 f0 = h4_to_f4(x0);
        acc0.x += c0.v * f0.x; acc0.y += c0.v * f0.y;
        acc0.z += c0.v * f0.z; acc0.w += c0.v * f0.w;
    }
    float4 acc = make_float4(acc0.x + acc1.x, acc0.y + acc1.y,
                             acc0.z + acc1.z, acc0.w + acc1.w);
    if (MODE == 0) {
        float4 b = ((const float4*)auxf)[lane];
        acc.x = fmaxf(acc.x + b.x, 0.f);
        acc.y = fmaxf(acc.y + b.y, 0.f);
        acc.z = fmaxf(acc.z + b.z, 0.f);
        acc.w = fmaxf(acc.w + b.w, 0.f);
    } else {
        h4 h0 = ((const h4*)auxh)[(size_t)gid * 64 + lane];
        float4 f = h4_to_f4(h0);
        acc.x = 0.9f * acc.x + 0.1f * f.x;
        acc.y = 0.9f * acc.y + 0.1f * f.y;
        acc.z = 0.9f * acc.z + 0.1f * f.z;
        acc.w = 0.9f * acc.w + 0.1f * f.w;
    }
    ((h4*)out)[(size_t)gid * 64 + lane] = f4_to_h4(acc);
}

// ---- final: logits = h @ fc_w + fc_b ; log_softmax ------------------------

__global__ __launch_bounds__(256) void k_final(const _Float16* __restrict__ h,
                                               const float* __restrict__ fcw,
                                               const float* __restrict__ fcb,
                                               float* __restrict__ out, int N) {
    __shared__ float ws[D * C];        // 40 KB
    __shared__ float bs[C];
    for (int i = threadIdx.x; i < D * C; i += blockDim.x) ws[i] = fcw[i];
    for (int i = threadIdx.x; i < C; i += blockDim.x) bs[i] = fcb[i];
    __syncthreads();
    int row = blockIdx.x * blockDim.x + threadIdx.x;
    if (row >= N) return;
    float acc[C];
    #pragma unroll
    for (int c = 0; c < C; ++c) acc[c] = bs[c];
    const _Float16* hr = h + (size_t)row * D;
    for (int k = 0; k < D; ++k) {
        float hv = (float)hr[k];
        #pragma unroll
        for (int c = 0; c < C; ++c) acc[c] += hv * ws[k * C + c];
    }
    float m = acc[0];
    #pragma unroll
    for (int c = 1; c < C; ++c) m = fmaxf(m, acc[c]);
    float s = 0.f;
    #pragma unroll
    for (int c = 0; c < C; ++c) s += expf(acc[c] - m);
    float lse = logf(s) + m;
    float* orow = out + (size_t)row * C;
    #pragma unroll
    for (int c = 0; c < C; ++c) orow[c] = acc[c] - lse;
}

// ---------------------------------------------------------------------------

extern "C" void kernel_launch(void* const* d_in, const int* in_sizes, int n_in,
                              void* d_out, int out_size, void* d_ws, size_t ws_size,
                              hipStream_t stream) {
    const float* x   = (const float*)d_in[0];
    const int*   ei  = (const int*)d_in[1];
    const float* w1  = (const float*)d_in[2];
    const float* b1  = (const float*)d_in[3];
    const float* w2  = (const float*)d_in[4];
    const float* b2  = (const float*)d_in[5];
    const float* w3  = (const float*)d_in[6];
    const float* b3  = (const float*)d_in[7];
    const float* fcw = (const float*)d_in[8];
    const float* fcb = (const float*)d_in[9];
    float* out = (float*)d_out;

    const int N = in_sizes[0] / D;
    const int E = in_sizes[1] / 2;
    const int* srcArr = ei;
    const int* dstArr = ei + E;

    char* wsp = (char*)d_ws;
    size_t off = 0;
    auto take = [&](size_t bytes) -> void* {
        void* p = wsp + off;
        off = (off + bytes + 255) & ~(size_t)255;
        return p;
    };
    int*       cnt    = (int*)take((size_t)N * 4);
    int*       rowptr = (int*)take((size_t)(N + 1) * 4);
    float*     dinv   = (float*)take((size_t)N * 4);
    EdgeCV*    edges  = (EdgeCV*)take((size_t)(E + N) * 8);
    _Float16*  bufA   = (_Float16*)take((size_t)N * D * 2);
    _Float16*  bufB   = (_Float16*)take((size_t)N * D * 2);
    _Float16*  bufC   = (_Float16*)take((size_t)N * D * 2);
    (void)ws_size;

    dim3 b256(256);
    int gN = (N + 255) / 256;
    int gE = (E + 255) / 256;

    // CSR build
    k_init_cnt<<<gN, b256, 0, stream>>>(cnt, N);
    k_count<<<gE, b256, 0, stream>>>(dstArr, cnt, E);
    k_scan<<<1, 1024, 0, stream>>>(cnt, rowptr, N);
    k_dinv<<<gN, b256, 0, stream>>>(cnt, dinv, N);
    k_fill_self<<<gN, b256, 0, stream>>>(rowptr, dinv, edges, cnt, N);
    k_fill_edges<<<gE, b256, 0, stream>>>(srcArr, dstArr, rowptr, dinv, edges, cnt, E);

    dim3 gemmGrid((N + BM - 1) / BM, D / BN);
    int spBlocks = (N + 3) / 4;        // 4 waves/block, wave per row

    // GCN layer 1..3 (bias+relu fused into SpMM epilogue)
    k_gemm<float><<<gemmGrid, b256, 0, stream>>>(x, w1, bufA, N);
    k_spmm<0><<<spBlocks, b256, 0, stream>>>(bufA, rowptr, edges, b1, nullptr, bufB, N);
    k_gemm<_Float16><<<gemmGrid, b256, 0, stream>>>(bufB, w2, bufA, N);
    k_spmm<0><<<spBlocks, b256, 0, stream>>>(bufA, rowptr, edges, b2, nullptr, bufB, N);
    k_gemm<_Float16><<<gemmGrid, b256, 0, stream>>>(bufB, w3, bufA, N);
    k_spmm<0><<<spBlocks, b256, 0, stream>>>(bufA, rowptr, edges, b3, nullptr, bufC, N);  // h0

    // APPNP: h <- 0.9 * A_hat h + 0.1 * h0
    const _Float16* cur = bufC;
    _Float16* nxt = bufA;
    for (int it = 0; it < 10; ++it) {
        k_spmm<1><<<spBlocks, b256, 0, stream>>>(cur, rowptr, edges, nullptr, bufC, nxt, N);
        cur = nxt;
        nxt = (nxt == bufA) ? bufB : bufA;
    }

    // final linear + log_softmax
    k_final<<<gN, b256, 0, stream>>>(cur, fcw, fcb, out, N);
}

// Round 4
// 2758.584 us; speedup vs baseline: 2.6219x; 1.5529x over previous
//
#include <hip/hip_runtime.h>
#include <math.h>

// ---------------------------------------------------------------------------
// APPNP + 3-layer GCN on MI355X.
// Round 4 changes:
//  (a) APPNP commuted with final projection: z0 = h0 @ fc_w (N x 40), then
//      z_{k+1} = 0.9 A z_k + 0.1 z0 on 40-dim rows (6.4x less gather volume).
//      Exact by linearity: (A h) @ W = A (h @ W). fcb added at the end.
//  (b) GCN linear layers via MFMA fp16 (16x16x32), W transposed to fp16 Wt[n][k],
//      K-strip LDS staging, A fragments prefetched to registers.
//  (c) SpMM gather unrolled 4-wide for memory-level parallelism.
// ---------------------------------------------------------------------------

constexpr int D = 256;   // feature / hidden dim
constexpr int C = 40;    // classes

typedef _Float16 h2v    __attribute__((ext_vector_type(2)));
typedef _Float16 h4     __attribute__((ext_vector_type(4)));
typedef _Float16 half8v __attribute__((ext_vector_type(8)));
typedef float    f32x4  __attribute__((ext_vector_type(4)));

struct __align__(8) EdgeCV { int c; float v; };

// ---- CSR build ------------------------------------------------------------

__global__ void k_init_cnt(int* __restrict__ cnt, int N) {
    int i = blockIdx.x * blockDim.x + threadIdx.x;
    if (i < N) cnt[i] = 1;            // self loop contributes 1 to in-degree
}

__global__ void k_count(const int* __restrict__ dst, int* __restrict__ cnt, int E) {
    int e = blockIdx.x * blockDim.x + threadIdx.x;
    if (e < E) atomicAdd(&cnt[dst[e]], 1);
}

// single-block exclusive scan over N counts -> rowptr[0..N]
__global__ __launch_bounds__(1024) void k_scan(const int* __restrict__ cnt,
                                               int* __restrict__ rowptr, int N) {
    __shared__ int sm[1024];
    const int tid = threadIdx.x;
    int offset = 0;
    for (int base = 0; base < N; base += 1024) {
        int i = base + tid;
        int v = (i < N) ? cnt[i] : 0;
        sm[tid] = v;
        #pragma unroll 1
        for (int s = 1; s < 1024; s <<= 1) {
            __syncthreads();
            int t = (tid >= s) ? sm[tid - s] : 0;
            __syncthreads();
            sm[tid] += t;
        }
        int incl = sm[tid];
        if (i < N) rowptr[i] = offset + incl - v;
        __syncthreads();
        offset += sm[1023];
        __syncthreads();
    }
    if (tid == 0) rowptr[N] = offset;
}

__global__ void k_dinv(const int* __restrict__ cnt, float* __restrict__ dinv, int N) {
    int i = blockIdx.x * blockDim.x + threadIdx.x;
    if (i < N) dinv[i] = rsqrtf((float)cnt[i]);
}

__global__ void k_fill_self(const int* __restrict__ rowptr, const float* __restrict__ dinv,
                            EdgeCV* __restrict__ edges, int* __restrict__ fill, int N) {
    int i = blockIdx.x * blockDim.x + threadIdx.x;
    if (i < N) {
        float dv = dinv[i];
        EdgeCV e; e.c = i; e.v = dv * dv;
        edges[rowptr[i]] = e;
        fill[i] = 1;
    }
}

__global__ void k_fill_edges(const int* __restrict__ src, const int* __restrict__ dst,
                             const int* __restrict__ rowptr, const float* __restrict__ dinv,
                             EdgeCV* __restrict__ edges, int* __restrict__ fill, int E) {
    int e = blockIdx.x * blockDim.x + threadIdx.x;
    if (e < E) {
        int s = src[e], d = dst[e];
        int slot = atomicAdd(&fill[d], 1);
        EdgeCV ev; ev.c = s; ev.v = dinv[s] * dinv[d];
        edges[rowptr[d] + slot] = ev;
    }
}

// ---- W transpose: W[k][n] fp32 -> Wt[n][k] fp16 (256x256) -----------------

__global__ void k_transW(const float* __restrict__ W, _Float16* __restrict__ Wt) {
    int n = blockIdx.x;
    int k = threadIdx.x;
    Wt[n * 256 + k] = (_Float16)W[k * 256 + n];
}

// ---- MFMA GEMM: Cout_fp16[M x 256] = A[M x 256] @ W (via Wt[n][k] fp16) ---
// block = 256 threads (4 waves), 128 rows/block, full N=256, fp32 accumulate.
// Fragment map (learn_hip m89/m92 verified):
//   A frag: lane l holds A[l&15][8*(l>>4)+j], j=0..7 (contiguous k)
//   B frag: lane l holds B[8*(l>>4)+j][l&15]  == Wt[l&15][8*(l>>4)+j]
//   C/D:    lane l reg r -> row 4*(l>>4)+r, col l&15

template <typename TIN>
__global__ __launch_bounds__(256, 1) void k_gemm_mfma(const TIN* __restrict__ A,
                                                      const _Float16* __restrict__ Wt,
                                                      _Float16* __restrict__ Cout, int M) {
    __shared__ _Float16 wlds[256][72];   // n-major K-strip of 64 (+8 pad -> 2-way banks)
    const int tid  = threadIdx.x;
    const int lane = tid & 63;
    const int wave = tid >> 6;
    const int l15  = lane & 15;
    const int lk8  = (lane >> 4) * 8;
    const int rowbase = blockIdx.x * 128 + wave * 32;

    // prefetch all A fragments (all loads issued before first use)
    half8v a[2][8];
    #pragma unroll
    for (int mt = 0; mt < 2; ++mt) {
        int row = rowbase + mt * 16 + l15;
        bool ok = row < M;
        const TIN* ap = A + (size_t)(ok ? row : 0) * D;
        #pragma unroll
        for (int kk = 0; kk < 8; ++kk) {
            half8v v;
            if constexpr (sizeof(TIN) == 2) {
                v = *(const half8v*)(ap + kk * 32 + lk8);
            } else {
                float4 f0 = *(const float4*)(ap + kk * 32 + lk8);
                float4 f1 = *(const float4*)(ap + kk * 32 + lk8 + 4);
                v[0] = (_Float16)f0.x; v[1] = (_Float16)f0.y;
                v[2] = (_Float16)f0.z; v[3] = (_Float16)f0.w;
                v[4] = (_Float16)f1.x; v[5] = (_Float16)f1.y;
                v[6] = (_Float16)f1.z; v[7] = (_Float16)f1.w;
            }
            if (!ok) {
                half8v zz = {0, 0, 0, 0, 0, 0, 0, 0};
                v = zz;
            }
            a[mt][kk] = v;
        }
    }

    f32x4 acc[2][16] = {};

    #pragma unroll
    for (int s = 0; s < 4; ++s) {       // K strips of 64
        {   // stage Wt[:, s*64 .. +63]: thread tid copies n-row tid (64 fp16)
            const half8v* src = (const half8v*)(Wt + (size_t)tid * D + s * 64);
            #pragma unroll
            for (int cc = 0; cc < 8; ++cc)
                *(half8v*)(&wlds[tid][cc * 8]) = src[cc];
        }
        __syncthreads();
        #pragma unroll
        for (int kf = 0; kf < 2; ++kf) {
            const int kk = s * 2 + kf;
            #pragma unroll
            for (int nt = 0; nt < 16; ++nt) {
                half8v b = *(const half8v*)(&wlds[nt * 16 + l15][kf * 32 + lk8]);
                acc[0][nt] = __builtin_amdgcn_mfma_f32_16x16x32_f16(a[0][kk], b, acc[0][nt], 0, 0, 0);
                acc[1][nt] = __builtin_amdgcn_mfma_f32_16x16x32_f16(a[1][kk], b, acc[1][nt], 0, 0, 0);
            }
        }
        __syncthreads();
    }

    const int r0 = (lane >> 4) * 4;
    #pragma unroll
    for (int mt = 0; mt < 2; ++mt) {
        #pragma unroll
        for (int r = 0; r < 4; ++r) {
            int row = rowbase + mt * 16 + r0 + r;
            if (row < M) {
                _Float16* crow = Cout + (size_t)row * D;
                #pragma unroll
                for (int nt = 0; nt < 16; ++nt)
                    crow[nt * 16 + l15] = (_Float16)acc[mt][nt][r];
            }
        }
    }
}

// ---- SpMM 256-dim (GCN): out = relu(sum_e v*h[col] + bias), wave/row ------

__global__ __launch_bounds__(256) void k_spmm_relu(const _Float16* __restrict__ h,
                                                   const int* __restrict__ rowptr,
                                                   const EdgeCV* __restrict__ edges,
                                                   const float* __restrict__ bias,
                                                   _Float16* __restrict__ out, int N) {
    int gid  = (int)((blockIdx.x * 256u + threadIdx.x) >> 6);
    int lane = threadIdx.x & 63;
    if (gid >= N) return;
    int start = rowptr[gid], end = rowptr[gid + 1];
    const h4* hp = (const h4*)h;
    float4 s0 = make_float4(0.f, 0.f, 0.f, 0.f);
    float4 s1 = make_float4(0.f, 0.f, 0.f, 0.f);
    float4 s2 = make_float4(0.f, 0.f, 0.f, 0.f);
    float4 s3 = make_float4(0.f, 0.f, 0.f, 0.f);
    int e = start;
    for (; e + 3 < end; e += 4) {        // 4 independent gathers in flight
        EdgeCV c0 = edges[e],     c1 = edges[e + 1];
        EdgeCV c2 = edges[e + 2], c3 = edges[e + 3];
        h4 x0 = hp[(size_t)c0.c * 64 + lane];
        h4 x1 = hp[(size_t)c1.c * 64 + lane];
        h4 x2 = hp[(size_t)c2.c * 64 + lane];
        h4 x3 = hp[(size_t)c3.c * 64 + lane];
        s0.x += c0.v * (float)x0[0]; s0.y += c0.v * (float)x0[1];
        s0.z += c0.v * (float)x0[2]; s0.w += c0.v * (float)x0[3];
        s1.x += c1.v * (float)x1[0]; s1.y += c1.v * (float)x1[1];
        s1.z += c1.v * (float)x1[2]; s1.w += c1.v * (float)x1[3];
        s2.x += c2.v * (float)x2[0]; s2.y += c2.v * (float)x2[1];
        s2.z += c2.v * (float)x2[2]; s2.w += c2.v * (float)x2[3];
        s3.x += c3.v * (float)x3[0]; s3.y += c3.v * (float)x3[1];
        s3.z += c3.v * (float)x3[2]; s3.w += c3.v * (float)x3[3];
    }
    for (; e < end; ++e) {
        EdgeCV c0 = edges[e];
        h4 x0 = hp[(size_t)c0.c * 64 + lane];
        s0.x += c0.v * (float)x0[0]; s0.y += c0.v * (float)x0[1];
        s0.z += c0.v * (float)x0[2]; s0.w += c0.v * (float)x0[3];
    }
    float4 acc = make_float4(s0.x + s1.x + s2.x + s3.x,
                             s0.y + s1.y + s2.y + s3.y,
                             s0.z + s1.z + s2.z + s3.z,
                             s0.w + s1.w + s2.w + s3.w);
    float4 b = ((const float4*)bias)[lane];
    h4 o;
    o[0] = (_Float16)fmaxf(acc.x + b.x, 0.f);
    o[1] = (_Float16)fmaxf(acc.y + b.y, 0.f);
    o[2] = (_Float16)fmaxf(acc.z + b.z, 0.f);
    o[3] = (_Float16)fmaxf(acc.w + b.w, 0.f);
    ((h4*)out)[(size_t)gid * 64 + lane] = o;
}

// ---- projection z0 = h0 @ fc_w (N x 40), fp32 acc, fp16 out ---------------

__global__ __launch_bounds__(256) void k_z0(const _Float16* __restrict__ h,
                                            const float* __restrict__ fcw,
                                            _Float16* __restrict__ z0, int N) {
    __shared__ float ws[D * C];          // 40 KB
    for (int i = threadIdx.x; i < D * C; i += 256) ws[i] = fcw[i];
    __syncthreads();
    int row = blockIdx.x * 256 + threadIdx.x;
    if (row >= N) return;
    float acc[C] = {};
    const half8v* hr = (const half8v*)(h + (size_t)row * D);
    for (int kq = 0; kq < 32; ++kq) {
        half8v v = hr[kq];
        #pragma unroll
        for (int j = 0; j < 8; ++j) {
            float hv = (float)v[j];
            #pragma unroll
            for (int c = 0; c < C; ++c) acc[c] += hv * ws[(kq * 8 + j) * C + c];
        }
    }
    h2v* zr = (h2v*)(z0 + (size_t)row * C);
    #pragma unroll
    for (int c = 0; c < 20; ++c) {
        h2v o; o[0] = (_Float16)acc[2 * c]; o[1] = (_Float16)acc[2 * c + 1];
        zr[c] = o;
    }
}

// ---- SpMM 40-dim (APPNP): out = 0.9*sum_e v*z[col] + 0.1*z0, wave/row -----
// lanes 0..19 active, 2 fp16 features per lane.

__global__ __launch_bounds__(256) void k_spmm40(const _Float16* __restrict__ z,
                                                const int* __restrict__ rowptr,
                                                const EdgeCV* __restrict__ edges,
                                                const _Float16* __restrict__ z0,
                                                _Float16* __restrict__ out, int N) {
    int gid  = (int)((blockIdx.x * 256u + threadIdx.x) >> 6);
    int lane = threadIdx.x & 63;
    if (gid >= N) return;
    int start = rowptr[gid], end = rowptr[gid + 1];
    const bool act = lane < 20;
    const h2v* zp = (const h2v*)z;
    float ax0 = 0.f, ay0 = 0.f, ax1 = 0.f, ay1 = 0.f;
    float ax2 = 0.f, ay2 = 0.f, ax3 = 0.f, ay3 = 0.f;
    int e = start;
    for (; e + 3 < end; e += 4) {
        EdgeCV c0 = edges[e],     c1 = edges[e + 1];
        EdgeCV c2 = edges[e + 2], c3 = edges[e + 3];
        if (act) {
            h2v x0 = zp[(size_t)c0.c * 20 + lane];
            h2v x1 = zp[(size_t)c1.c * 20 + lane];
            h2v x2 = zp[(size_t)c2.c * 20 + lane];
            h2v x3 = zp[(size_t)c3.c * 20 + lane];
            ax0 += c0.v * (float)x0[0]; ay0 += c0.v * (float)x0[1];
            ax1 += c1.v * (float)x1[0]; ay1 += c1.v * (float)x1[1];
            ax2 += c2.v * (float)x2[0]; ay2 += c2.v * (float)x2[1];
            ax3 += c3.v * (float)x3[0]; ay3 += c3.v * (float)x3[1];
        }
    }
    for (; e < end; ++e) {
        EdgeCV c0 = edges[e];
        if (act) {
            h2v x0 = zp[(size_t)c0.c * 20 + lane];
            ax0 += c0.v * (float)x0[0]; ay0 += c0.v * (float)x0[1];
        }
    }
    if (act) {
        float ax = ax0 + ax1 + ax2 + ax3;
        float ay = ay0 + ay1 + ay2 + ay3;
        h2v zz = ((const h2v*)z0)[(size_t)gid * 20 + lane];
        ax = 0.9f * ax + 0.1f * (float)zz[0];
        ay = 0.9f * ay + 0.1f * (float)zz[1];
        h2v o; o[0] = (_Float16)ax; o[1] = (_Float16)ay;
        ((h2v*)out)[(size_t)gid * 20 + lane] = o;
    }
}

// ---- final: out = log_softmax(z + fcb) ------------------------------------

__global__ __launch_bounds__(256) void k_logsm(const _Float16* __restrict__ z,
                                               const float* __restrict__ fcb,
                                               float* __restrict__ out, int N) {
    __shared__ float bs[C];
    for (int i = threadIdx.x; i < C; i += 256) bs[i] = fcb[i];
    __syncthreads();
    int row = blockIdx.x * 256 + threadIdx.x;
    if (row >= N) return;
    float v[C];
    const h2v* zr = (const h2v*)(z + (size_t)row * C);
    #pragma unroll
    for (int c = 0; c < 20; ++c) {
        h2v t = zr[c];
        v[2 * c]     = (float)t[0] + bs[2 * c];
        v[2 * c + 1] = (float)t[1] + bs[2 * c + 1];
    }
    float m = v[0];
    #pragma unroll
    for (int c = 1; c < C; ++c) m = fmaxf(m, v[c]);
    float s = 0.f;
    #pragma unroll
    for (int c = 0; c < C; ++c) s += expf(v[c] - m);
    float lse = logf(s) + m;
    float* orow = out + (size_t)row * C;
    #pragma unroll
    for (int c = 0; c < C; ++c) orow[c] = v[c] - lse;
}

// ---------------------------------------------------------------------------

extern "C" void kernel_launch(void* const* d_in, const int* in_sizes, int n_in,
                              void* d_out, int out_size, void* d_ws, size_t ws_size,
                              hipStream_t stream) {
    const float* x   = (const float*)d_in[0];
    const int*   ei  = (const int*)d_in[1];
    const float* w1  = (const float*)d_in[2];
    const float* b1  = (const float*)d_in[3];
    const float* w2  = (const float*)d_in[4];
    const float* b2  = (const float*)d_in[5];
    const float* w3  = (const float*)d_in[6];
    const float* b3  = (const float*)d_in[7];
    const float* fcw = (const float*)d_in[8];
    const float* fcb = (const float*)d_in[9];
    float* out = (float*)d_out;

    const int N = in_sizes[0] / D;
    const int E = in_sizes[1] / 2;
    const int* srcArr = ei;
    const int* dstArr = ei + E;

    char* wsp = (char*)d_ws;
    size_t off = 0;
    auto take = [&](size_t bytes) -> void* {
        void* p = wsp + off;
        off = (off + bytes + 255) & ~(size_t)255;
        return p;
    };
    int*       cnt    = (int*)take((size_t)N * 4);
    int*       rowptr = (int*)take((size_t)(N + 1) * 4);
    float*     dinv   = (float*)take((size_t)N * 4);
    EdgeCV*    edges  = (EdgeCV*)take((size_t)(E + N) * 8);
    _Float16*  bufA   = (_Float16*)take((size_t)N * D * 2);
    _Float16*  bufB   = (_Float16*)take((size_t)N * D * 2);
    _Float16*  bufC   = (_Float16*)take((size_t)N * D * 2);
    _Float16*  Wt1    = (_Float16*)take((size_t)D * D * 2);
    _Float16*  Wt2    = (_Float16*)take((size_t)D * D * 2);
    _Float16*  Wt3    = (_Float16*)take((size_t)D * D * 2);
    _Float16*  z0w    = (_Float16*)take((size_t)N * C * 2);
    _Float16*  zA     = (_Float16*)take((size_t)N * C * 2);
    _Float16*  zB     = (_Float16*)take((size_t)N * C * 2);
    (void)ws_size;

    dim3 b256(256);
    int gN = (N + 255) / 256;
    int gE = (E + 255) / 256;

    // CSR build
    k_init_cnt<<<gN, b256, 0, stream>>>(cnt, N);
    k_count<<<gE, b256, 0, stream>>>(dstArr, cnt, E);
    k_scan<<<1, 1024, 0, stream>>>(cnt, rowptr, N);
    k_dinv<<<gN, b256, 0, stream>>>(cnt, dinv, N);
    k_fill_self<<<gN, b256, 0, stream>>>(rowptr, dinv, edges, cnt, N);
    k_fill_edges<<<gE, b256, 0, stream>>>(srcArr, dstArr, rowptr, dinv, edges, cnt, E);

    // weight transposes (fp32 -> fp16, n-major)
    k_transW<<<256, b256, 0, stream>>>(w1, Wt1);
    k_transW<<<256, b256, 0, stream>>>(w2, Wt2);
    k_transW<<<256, b256, 0, stream>>>(w3, Wt3);

    dim3 gg((N + 127) / 128);
    int spBlocks = (N + 3) / 4;        // 4 waves/block, wave per row

    // GCN layers (bias+relu fused into SpMM epilogue)
    k_gemm_mfma<float><<<gg, b256, 0, stream>>>(x, Wt1, bufA, N);
    k_spmm_relu<<<spBlocks, b256, 0, stream>>>(bufA, rowptr, edges, b1, bufB, N);
    k_gemm_mfma<_Float16><<<gg, b256, 0, stream>>>(bufB, Wt2, bufA, N);
    k_spmm_relu<<<spBlocks, b256, 0, stream>>>(bufA, rowptr, edges, b2, bufB, N);
    k_gemm_mfma<_Float16><<<gg, b256, 0, stream>>>(bufB, Wt3, bufA, N);
    k_spmm_relu<<<spBlocks, b256, 0, stream>>>(bufA, rowptr, edges, b3, bufC, N);  // h0

    // project: z0 = h0 @ fc_w  (bias added at the end)
    k_z0<<<gN, b256, 0, stream>>>(bufC, fcw, z0w, N);

    // APPNP on 40-dim z: z <- 0.9 * A_hat z + 0.1 * z0
    const _Float16* zc = z0w;
    _Float16* zn = zA;
    for (int it = 0; it < 10; ++it) {
        k_spmm40<<<spBlocks, b256, 0, stream>>>(zc, rowptr, edges, z0w, zn, N);
        zc = zn;
        zn = (zn == zA) ? zB : zA;
    }

    // final: log_softmax(z + fcb)
    k_logsm<<<gN, b256, 0, stream>>>(zc, fcb, out, N);
}

// Round 6
// 2093.324 us; speedup vs baseline: 3.4551x; 1.3178x over previous
//
#include <hip/hip_runtime.h>
#include <math.h>

// ---------------------------------------------------------------------------
// APPNP + 3-layer GCN on MI355X.
// Round 5 changes (resubmitted unchanged after broker timeout):
//  (a) spmm40: z rows padded to 64 fp16 (128 B = 1 L2 line), 2 rows per wave
//      (half-wave each, 32 lanes x 4B = full line). Kills line-straddle +
//      idle lanes of the 40-dim propagate.
//  (b) CSR segment allocation via atomicAdd cursor (order-free) instead of
//      the serial single-block scan. SpMM uses start[i] / start[i]+cnt[i].
//  (c) dinv + self-loop fused; one transW kernel for all 3 weights.
// Carried: fp16 h buffers (L3-resident), MFMA fp16 GEMM, APPNP commuted with
// final projection (40-dim propagate), 4-wide gather unroll.
// ---------------------------------------------------------------------------

constexpr int D  = 256;   // feature / hidden dim
constexpr int C  = 40;    // classes
constexpr int ZP = 64;    // padded z row (fp16 elems) = 128 B

typedef _Float16 h2v    __attribute__((ext_vector_type(2)));
typedef _Float16 h4     __attribute__((ext_vector_type(4)));
typedef _Float16 half8v __attribute__((ext_vector_type(8)));
typedef float    f32x4  __attribute__((ext_vector_type(4)));

struct __align__(8) EdgeCV { int c; float v; };

// ---- CSR build (order-free segment alloc) ---------------------------------

__global__ void k_init_cnt(int* __restrict__ cnt, int N) {
    int i = blockIdx.x * blockDim.x + threadIdx.x;
    if (i < N) cnt[i] = 1;            // self loop contributes 1 to in-degree
}

__global__ void k_count(const int* __restrict__ dst, int* __restrict__ cnt, int E) {
    int e = blockIdx.x * blockDim.x + threadIdx.x;
    if (e < E) atomicAdd(&cnt[dst[e]], 1);
}

__global__ void k_alloc(const int* __restrict__ cnt, int* __restrict__ startA,
                        int* __restrict__ cursor, int N) {
    int i = blockIdx.x * blockDim.x + threadIdx.x;
    if (i < N) startA[i] = atomicAdd(cursor, cnt[i]);
}

// dinv + self-loop edge + fill-counter init, one pass
__global__ void k_selfinit(const int* __restrict__ cnt, const int* __restrict__ startA,
                           float* __restrict__ dinv, EdgeCV* __restrict__ edges,
                           int* __restrict__ fill, int N) {
    int i = blockIdx.x * blockDim.x + threadIdx.x;
    if (i < N) {
        float dv = rsqrtf((float)cnt[i]);
        dinv[i] = dv;
        EdgeCV e; e.c = i; e.v = dv * dv;
        edges[startA[i]] = e;
        fill[i] = 1;
    }
}

__global__ void k_fill_edges(const int* __restrict__ src, const int* __restrict__ dst,
                             const int* __restrict__ startA, const float* __restrict__ dinv,
                             EdgeCV* __restrict__ edges, int* __restrict__ fill, int E) {
    int e = blockIdx.x * blockDim.x + threadIdx.x;
    if (e < E) {
        int s = src[e], d = dst[e];
        int slot = atomicAdd(&fill[d], 1);
        EdgeCV ev; ev.c = s; ev.v = dinv[s] * dinv[d];
        edges[startA[d] + slot] = ev;
    }
}

// ---- W transpose: W[k][n] fp32 -> Wt[w][n][k] fp16 (3 x 256 x 256) --------

__global__ void k_transW(const float* __restrict__ W0, const float* __restrict__ W1,
                         const float* __restrict__ W2, _Float16* __restrict__ Wt) {
    int n = blockIdx.x;
    int w = blockIdx.y;
    int k = threadIdx.x;
    const float* W = (w == 0) ? W0 : (w == 1) ? W1 : W2;
    Wt[(size_t)w * 65536 + n * 256 + k] = (_Float16)W[k * 256 + n];
}

// ---- MFMA GEMM: Cout_fp16[M x 256] = A[M x 256] @ W (via Wt[n][k] fp16) ---
// block = 256 threads (4 waves), 128 rows/block, full N=256, fp32 accumulate.
// Fragment map (learn_hip m89/m92 verified):
//   A frag: lane l holds A[l&15][8*(l>>4)+j], j=0..7 (contiguous k)
//   B frag: lane l holds B[8*(l>>4)+j][l&15]  == Wt[l&15][8*(l>>4)+j]
//   C/D:    lane l reg r -> row 4*(l>>4)+r, col l&15

template <typename TIN>
__global__ __launch_bounds__(256, 1) void k_gemm_mfma(const TIN* __restrict__ A,
                                                      const _Float16* __restrict__ Wt,
                                                      _Float16* __restrict__ Cout, int M) {
    __shared__ _Float16 wlds[256][72];   // n-major K-strip of 64 (+8 pad)
    const int tid  = threadIdx.x;
    const int lane = tid & 63;
    const int wave = tid >> 6;
    const int l15  = lane & 15;
    const int lk8  = (lane >> 4) * 8;
    const int rowbase = blockIdx.x * 128 + wave * 32;

    half8v a[2][8];
    #pragma unroll
    for (int mt = 0; mt < 2; ++mt) {
        int row = rowbase + mt * 16 + l15;
        bool ok = row < M;
        const TIN* ap = A + (size_t)(ok ? row : 0) * D;
        #pragma unroll
        for (int kk = 0; kk < 8; ++kk) {
            half8v v;
            if constexpr (sizeof(TIN) == 2) {
                v = *(const half8v*)(ap + kk * 32 + lk8);
            } else {
                float4 f0 = *(const float4*)(ap + kk * 32 + lk8);
                float4 f1 = *(const float4*)(ap + kk * 32 + lk8 + 4);
                v[0] = (_Float16)f0.x; v[1] = (_Float16)f0.y;
                v[2] = (_Float16)f0.z; v[3] = (_Float16)f0.w;
                v[4] = (_Float16)f1.x; v[5] = (_Float16)f1.y;
                v[6] = (_Float16)f1.z; v[7] = (_Float16)f1.w;
            }
            if (!ok) {
                half8v zz = {0, 0, 0, 0, 0, 0, 0, 0};
                v = zz;
            }
            a[mt][kk] = v;
        }
    }

    f32x4 acc[2][16] = {};

    #pragma unroll
    for (int s = 0; s < 4; ++s) {       // K strips of 64
        {
            const half8v* srcp = (const half8v*)(Wt + (size_t)tid * D + s * 64);
            #pragma unroll
            for (int cc = 0; cc < 8; ++cc)
                *(half8v*)(&wlds[tid][cc * 8]) = srcp[cc];
        }
        __syncthreads();
        #pragma unroll
        for (int kf = 0; kf < 2; ++kf) {
            const int kk = s * 2 + kf;
            #pragma unroll
            for (int nt = 0; nt < 16; ++nt) {
                half8v b = *(const half8v*)(&wlds[nt * 16 + l15][kf * 32 + lk8]);
                acc[0][nt] = __builtin_amdgcn_mfma_f32_16x16x32_f16(a[0][kk], b, acc[0][nt], 0, 0, 0);
                acc[1][nt] = __builtin_amdgcn_mfma_f32_16x16x32_f16(a[1][kk], b, acc[1][nt], 0, 0, 0);
            }
        }
        __syncthreads();
    }

    const int r0 = (lane >> 4) * 4;
    #pragma unroll
    for (int mt = 0; mt < 2; ++mt) {
        #pragma unroll
        for (int r = 0; r < 4; ++r) {
            int row = rowbase + mt * 16 + r0 + r;
            if (row < M) {
                _Float16* crow = Cout + (size_t)row * D;
                #pragma unroll
                for (int nt = 0; nt < 16; ++nt)
                    crow[nt * 16 + l15] = (_Float16)acc[mt][nt][r];
            }
        }
    }
}

// ---- SpMM 256-dim (GCN): out = relu(sum_e v*h[col] + bias), wave/row ------

__global__ __launch_bounds__(256) void k_spmm_relu(const _Float16* __restrict__ h,
                                                   const int* __restrict__ startA,
                                                   const int* __restrict__ cnt,
                                                   const EdgeCV* __restrict__ edges,
                                                   const float* __restrict__ bias,
                                                   _Float16* __restrict__ out, int N) {
    int gid  = (int)((blockIdx.x * 256u + threadIdx.x) >> 6);
    int lane = threadIdx.x & 63;
    if (gid >= N) return;
    int start = startA[gid], end = start + cnt[gid];
    const h4* hp = (const h4*)h;
    float4 s0 = make_float4(0.f, 0.f, 0.f, 0.f);
    float4 s1 = make_float4(0.f, 0.f, 0.f, 0.f);
    float4 s2 = make_float4(0.f, 0.f, 0.f, 0.f);
    float4 s3 = make_float4(0.f, 0.f, 0.f, 0.f);
    int e = start;
    for (; e + 3 < end; e += 4) {        // 4 independent gathers in flight
        EdgeCV c0 = edges[e],     c1 = edges[e + 1];
        EdgeCV c2 = edges[e + 2], c3 = edges[e + 3];
        h4 x0 = hp[(size_t)c0.c * 64 + lane];
        h4 x1 = hp[(size_t)c1.c * 64 + lane];
        h4 x2 = hp[(size_t)c2.c * 64 + lane];
        h4 x3 = hp[(size_t)c3.c * 64 + lane];
        s0.x += c0.v * (float)x0[0]; s0.y += c0.v * (float)x0[1];
        s0.z += c0.v * (float)x0[2]; s0.w += c0.v * (float)x0[3];
        s1.x += c1.v * (float)x1[0]; s1.y += c1.v * (float)x1[1];
        s1.z += c1.v * (float)x1[2]; s1.w += c1.v * (float)x1[3];
        s2.x += c2.v * (float)x2[0]; s2.y += c2.v * (float)x2[1];
        s2.z += c2.v * (float)x2[2]; s2.w += c2.v * (float)x2[3];
        s3.x += c3.v * (float)x3[0]; s3.y += c3.v * (float)x3[1];
        s3.z += c3.v * (float)x3[2]; s3.w += c3.v * (float)x3[3];
    }
    for (; e < end; ++e) {
        EdgeCV c0 = edges[e];
        h4 x0 = hp[(size_t)c0.c * 64 + lane];
        s0.x += c0.v * (float)x0[0]; s0.y += c0.v * (float)x0[1];
        s0.z += c0.v * (float)x0[2]; s0.w += c0.v * (float)x0[3];
    }
    float4 acc = make_float4(s0.x + s1.x + s2.x + s3.x,
                             s0.y + s1.y + s2.y + s3.y,
                             s0.z + s1.z + s2.z + s3.z,
                             s0.w + s1.w + s2.w + s3.w);
    float4 b = ((const float4*)bias)[lane];
    h4 o;
    o[0] = (_Float16)fmaxf(acc.x + b.x, 0.f);
    o[1] = (_Float16)fmaxf(acc.y + b.y, 0.f);
    o[2] = (_Float16)fmaxf(acc.z + b.z, 0.f);
    o[3] = (_Float16)fmaxf(acc.w + b.w, 0.f);
    ((h4*)out)[(size_t)gid * 64 + lane] = o;
}

// ---- projection z0 = h0 @ fc_w (N x 40), padded to ZP, fp32 acc -----------

__global__ __launch_bounds__(256) void k_z0(const _Float16* __restrict__ h,
                                            const float* __restrict__ fcw,
                                            _Float16* __restrict__ z0, int N) {
    __shared__ float ws[D * C];          // 40 KB
    for (int i = threadIdx.x; i < D * C; i += 256) ws[i] = fcw[i];
    __syncthreads();
    int row = blockIdx.x * 256 + threadIdx.x;
    if (row >= N) return;
    float acc[C] = {};
    const half8v* hr = (const half8v*)(h + (size_t)row * D);
    for (int kq = 0; kq < 32; ++kq) {
        half8v v = hr[kq];
        #pragma unroll
        for (int j = 0; j < 8; ++j) {
            float hv = (float)v[j];
            #pragma unroll
            for (int c = 0; c < C; ++c) acc[c] += hv * ws[(kq * 8 + j) * C + c];
        }
    }
    h2v* zr = (h2v*)(z0 + (size_t)row * ZP);
    #pragma unroll
    for (int c = 0; c < 20; ++c) {
        h2v o; o[0] = (_Float16)acc[2 * c]; o[1] = (_Float16)acc[2 * c + 1];
        zr[c] = o;
    }
    h2v zz = {(_Float16)0.f, (_Float16)0.f};
    #pragma unroll
    for (int c = 20; c < 32; ++c) zr[c] = zz;   // zero the pad
}

// ---- SpMM 40-dim padded (APPNP): 2 rows/wave, 32 lanes x 4B = 1 line ------
// out = 0.9*sum_e v*z[col] + 0.1*z0   (pad columns stay zero)

__global__ __launch_bounds__(256) void k_spmm40(const _Float16* __restrict__ z,
                                                const int* __restrict__ startA,
                                                const int* __restrict__ cnt,
                                                const EdgeCV* __restrict__ edges,
                                                const _Float16* __restrict__ z0,
                                                _Float16* __restrict__ out, int N) {
    int wid  = (int)((blockIdx.x * 256u + threadIdx.x) >> 6);
    int lane = threadIdx.x & 63;
    int p    = lane >> 5;                 // half-wave -> row parity
    int l5   = lane & 31;
    int row  = wid * 2 + p;
    if (row >= N) return;
    int start = startA[row], end = start + cnt[row];
    const h2v* zp = (const h2v*)z;        // row stride ZP/2 = 32 h2v
    float ax0 = 0.f, ay0 = 0.f, ax1 = 0.f, ay1 = 0.f;
    float ax2 = 0.f, ay2 = 0.f, ax3 = 0.f, ay3 = 0.f;
    int e = start;
    for (; e + 3 < end; e += 4) {
        EdgeCV c0 = edges[e],     c1 = edges[e + 1];
        EdgeCV c2 = edges[e + 2], c3 = edges[e + 3];
        h2v x0 = zp[(size_t)c0.c * 32 + l5];
        h2v x1 = zp[(size_t)c1.c * 32 + l5];
        h2v x2 = zp[(size_t)c2.c * 32 + l5];
        h2v x3 = zp[(size_t)c3.c * 32 + l5];
        ax0 += c0.v * (float)x0[0]; ay0 += c0.v * (float)x0[1];
        ax1 += c1.v * (float)x1[0]; ay1 += c1.v * (float)x1[1];
        ax2 += c2.v * (float)x2[0]; ay2 += c2.v * (float)x2[1];
        ax3 += c3.v * (float)x3[0]; ay3 += c3.v * (float)x3[1];
    }
    for (; e < end; ++e) {
        EdgeCV c0 = edges[e];
        h2v x0 = zp[(size_t)c0.c * 32 + l5];
        ax0 += c0.v * (float)x0[0]; ay0 += c0.v * (float)x0[1];
    }
    float ax = ax0 + ax1 + ax2 + ax3;
    float ay = ay0 + ay1 + ay2 + ay3;
    h2v zz = ((const h2v*)z0)[(size_t)row * 32 + l5];
    ax = 0.9f * ax + 0.1f * (float)zz[0];
    ay = 0.9f * ay + 0.1f * (float)zz[1];
    h2v o; o[0] = (_Float16)ax; o[1] = (_Float16)ay;
    ((h2v*)out)[(size_t)row * 32 + l5] = o;
}

// ---- final: out = log_softmax(z + fcb) ------------------------------------

__global__ __launch_bounds__(256) void k_logsm(const _Float16* __restrict__ z,
                                               const float* __restrict__ fcb,
                                               float* __restrict__ out, int N) {
    __shared__ float bs[C];
    for (int i = threadIdx.x; i < C; i += 256) bs[i] = fcb[i];
    __syncthreads();
    int row = blockIdx.x * 256 + threadIdx.x;
    if (row >= N) return;
    float v[C];
    const h2v* zr = (const h2v*)(z + (size_t)row * ZP);
    #pragma unroll
    for (int c = 0; c < 20; ++c) {
        h2v t = zr[c];
        v[2 * c]     = (float)t[0] + bs[2 * c];
        v[2 * c + 1] = (float)t[1] + bs[2 * c + 1];
    }
    float m = v[0];
    #pragma unroll
    for (int c = 1; c < C; ++c) m = fmaxf(m, v[c]);
    float s = 0.f;
    #pragma unroll
    for (int c = 0; c < C; ++c) s += expf(v[c] - m);
    float lse = logf(s) + m;
    float* orow = out + (size_t)row * C;
    #pragma unroll
    for (int c = 0; c < C; ++c) orow[c] = v[c] - lse;
}

// ---------------------------------------------------------------------------

extern "C" void kernel_launch(void* const* d_in, const int* in_sizes, int n_in,
                              void* d_out, int out_size, void* d_ws, size_t ws_size,
                              hipStream_t stream) {
    const float* x   = (const float*)d_in[0];
    const int*   ei  = (const int*)d_in[1];
    const float* w1  = (const float*)d_in[2];
    const float* b1  = (const float*)d_in[3];
    const float* w2  = (const float*)d_in[4];
    const float* b2  = (const float*)d_in[5];
    const float* w3  = (const float*)d_in[6];
    const float* b3  = (const float*)d_in[7];
    const float* fcw = (const float*)d_in[8];
    const float* fcb = (const float*)d_in[9];
    float* out = (float*)d_out;

    const int N = in_sizes[0] / D;
    const int E = in_sizes[1] / 2;
    const int* srcArr = ei;
    const int* dstArr = ei + E;

    char* wsp = (char*)d_ws;
    size_t off = 0;
    auto take = [&](size_t bytes) -> void* {
        void* p = wsp + off;
        off = (off + bytes + 255) & ~(size_t)255;
        return p;
    };
    int*       cnt    = (int*)take((size_t)N * 4);
    int*       startA = (int*)take((size_t)N * 4);
    int*       fill   = (int*)take((size_t)N * 4);
    int*       cursor = (int*)take(256);
    float*     dinv   = (float*)take((size_t)N * 4);
    EdgeCV*    edges  = (EdgeCV*)take((size_t)(E + N) * 8);
    _Float16*  bufA   = (_Float16*)take((size_t)N * D * 2);
    _Float16*  bufB   = (_Float16*)take((size_t)N * D * 2);
    _Float16*  bufC   = (_Float16*)take((size_t)N * D * 2);
    _Float16*  Wt     = (_Float16*)take((size_t)3 * D * D * 2);
    _Float16*  z0w    = (_Float16*)take((size_t)N * ZP * 2);
    _Float16*  zA     = (_Float16*)take((size_t)N * ZP * 2);
    _Float16*  zB     = (_Float16*)take((size_t)N * ZP * 2);
    (void)ws_size;

    dim3 b256(256);
    int gN = (N + 255) / 256;
    int gE = (E + 255) / 256;

    // CSR build (order-free segment allocation, no scan)
    hipMemsetAsync(cursor, 0, 4, stream);
    k_init_cnt<<<gN, b256, 0, stream>>>(cnt, N);
    k_count<<<gE, b256, 0, stream>>>(dstArr, cnt, E);
    k_alloc<<<gN, b256, 0, stream>>>(cnt, startA, cursor, N);
    k_selfinit<<<gN, b256, 0, stream>>>(cnt, startA, dinv, edges, fill, N);
    k_fill_edges<<<gE, b256, 0, stream>>>(srcArr, dstArr, startA, dinv, edges, fill, E);

    // weight transposes (fp32 -> fp16, n-major), all three at once
    dim3 tg(256, 3);
    k_transW<<<tg, b256, 0, stream>>>(w1, w2, w3, Wt);

    dim3 gg((N + 127) / 128);
    int spBlocks  = (N + 3) / 4;       // wave per row (256-dim)
    int sp40Blocks = (N + 7) / 8;      // 2 rows per wave (40-dim padded)

    // GCN layers (bias+relu fused into SpMM epilogue)
    k_gemm_mfma<float><<<gg, b256, 0, stream>>>(x, Wt, bufA, N);
    k_spmm_relu<<<spBlocks, b256, 0, stream>>>(bufA, startA, cnt, edges, b1, bufB, N);
    k_gemm_mfma<_Float16><<<gg, b256, 0, stream>>>(bufB, Wt + 65536, bufA, N);
    k_spmm_relu<<<spBlocks, b256, 0, stream>>>(bufA, startA, cnt, edges, b2, bufB, N);
    k_gemm_mfma<_Float16><<<gg, b256, 0, stream>>>(bufB, Wt + 131072, bufA, N);
    k_spmm_relu<<<spBlocks, b256, 0, stream>>>(bufA, startA, cnt, edges, b3, bufC, N);  // h0

    // project: z0 = h0 @ fc_w  (bias added at the end), padded rows
    k_z0<<<gN, b256, 0, stream>>>(bufC, fcw, z0w, N);

    // APPNP on padded 40-dim z: z <- 0.9 * A_hat z + 0.1 * z0
    const _Float16* zc = z0w;
    _Float16* zn = zA;
    for (int it = 0; it < 10; ++it) {
        k_spmm40<<<sp40Blocks, b256, 0, stream>>>(zc, startA, cnt, edges, z0w, zn, N);
        zc = zn;
        zn = (zn == zA) ? zB : zA;
    }

    // final: log_softmax(z + fcb)
    k_logsm<<<gN, b256, 0, stream>>>(zc, fcb, out, N);
}